// Round 5
// baseline (171.695 us; speedup 1.0000x reference)
//
#include <hip/hip_runtime.h>
#include <stdint.h>

// BlockLinear: out = block_diag(blocks) @ inp + bias
//   inp (2048,8192) fp32 (dtype auto-detected), blocks (8,256,256), bias (2048,)
// R5: weights register-resident (loaded once per wave), b-loop software
// pipeline. 512 wgs x 512 thr; wave owns 32 m-rows (32x32x16 MFMA, 64 VGPR of
// weight frags). Per iter: stage 32-col inp chunk (coalesced dwords ->
// register transpose -> ds_write_b128, 2 LDS buffers), 16 b128 reads + 16
// MFMA, plain f32x4 stores (NO nontemporal: R4 showed nt breaks L2
// write-combining of 64B half-lines, +30% WRITE_SIZE). Loads for tile j+2
// issued during iter j -> one full iter of latency hiding. kb = wg&7 pins one
// weight block per XCD L2 for the one-time preload.

#define BCOLS 8192

typedef __attribute__((ext_vector_type(8))) short short8;             // 8 bf16
typedef __attribute__((ext_vector_type(4))) float f32x4;
typedef __attribute__((ext_vector_type(16))) float f32x16;            // 32x32 acc
typedef __attribute__((ext_vector_type(4))) unsigned short ushort4v;

__device__ __forceinline__ unsigned short f2bf(float x) {
  unsigned u = __builtin_bit_cast(unsigned, x);
  u += 0x7FFFu + ((u >> 16) & 1u);  // RNE
  return (unsigned short)(u >> 16);
}
__device__ __forceinline__ float bf2f(unsigned short h) {
  unsigned u = ((unsigned)h) << 16;
  return __builtin_bit_cast(float, u);
}
__device__ __forceinline__ unsigned pk2(float a, float b) {
  return (unsigned)f2bf(a) | ((unsigned)f2bf(b) << 16);
}

// bf16 data: bits[8:15] of each dword cluster in [0x3B,0x43] for N(0,1);
// fp32: uniform mantissa bits. 32-sample vote, wave-uniform.
__device__ __forceinline__ bool detect_bf16(const void* p) {
  const unsigned* u = (const unsigned*)p;
  int votes = 0;
#pragma unroll
  for (int i = 0; i < 32; ++i) {
    unsigned b = (u[i] >> 8) & 0x7Fu;
    votes += (b >= 0x3Bu && b <= 0x43u) ? 1 : 0;
  }
  return votes >= 16;
}

// Pre-pass: blocks (any dtype) -> bf16 copy in d_ws.
__global__ void bl_convw(const void* __restrict__ blocks,
                         unsigned short* __restrict__ wbf) {
  const int i = blockIdx.x * 256 + threadIdx.x;
  if (detect_bf16(blocks)) {
    ((ushort4v*)wbf)[i] = ((const ushort4v*)blocks)[i];
  } else {
    float4 v = ((const float4*)blocks)[i];
    ushort4v p = {f2bf(v.x), f2bf(v.y), f2bf(v.z), f2bf(v.w)};
    ((ushort4v*)wbf)[i] = p;
  }
}

// wg: kb = wg&7, b-range = (wg>>3)*128, 4 iters of 32 cols. 8 waves; wave w
// owns m rows [32w, 32w+32). A-op = inp^T (LDS, b-major k-contiguous):
// A[i=b=lane&31][k=(lane>>5)*8+e]. B-op = weights (regs): B[k][j=m=lane&31].
// D (32x32): col=lane&31=m, row b=(reg&3)+8*(reg>>2)+4*(lane>>5) -> 4
// consecutive b per reg quad -> f32x4 stores.
template <typename T, bool WBF>
__device__ __forceinline__ void run_bl(const T* __restrict__ inp,
                                       const T* __restrict__ blocks,
                                       const unsigned short* __restrict__ wbf,
                                       const T* __restrict__ bias,
                                       T* __restrict__ out,
                                       unsigned short (&Blds)[2][32][264]) {
  constexpr bool BF = (sizeof(T) == 2);
  const int t    = threadIdx.x;
  const int wg   = blockIdx.x;
  const int kb   = wg & 7;
  const int b0   = (wg >> 3) << 7;  // 128 cols per wg
  const int lane = t & 63;
  const int w    = t >> 6;          // wave 0..7
  const int l31  = lane & 31;
  const int q    = lane >> 5;       // half-wave
  const int m0   = w << 5;          // wave's 32-row m base

  // ---- one-time: weight fragments for all 16 k-steps into registers ----
  short8 wf[16];
  {
    const int mrow = m0 + l31;
    if constexpr (WBF) {
      const unsigned short* wr = wbf + kb * 65536 + mrow * 256 + q * 8;
#pragma unroll
      for (int kk = 0; kk < 16; ++kk) wf[kk] = *(const short8*)(wr + kk * 16);
    } else if constexpr (BF) {
      const unsigned short* wr =
          (const unsigned short*)blocks + kb * 65536 + mrow * 256 + q * 8;
#pragma unroll
      for (int kk = 0; kk < 16; ++kk) wf[kk] = *(const short8*)(wr + kk * 16);
    } else {
      const float* wr = (const float*)blocks + kb * 65536 + mrow * 256 + q * 8;
#pragma unroll
      for (int kk = 0; kk < 16; ++kk) {
        float4 w0 = *(const float4*)(wr + kk * 16);
        float4 w1 = *(const float4*)(wr + kk * 16 + 4);
        uint4 u = {pk2(w0.x, w0.y), pk2(w0.z, w0.w),
                   pk2(w1.x, w1.y), pk2(w1.z, w1.w)};
        wf[kk] = __builtin_bit_cast(short8, u);
      }
    }
  }

  const int mrow_g = kb * 256 + m0 + l31;  // this lane's output row (fixed)
  float bv;
  if constexpr (BF) bv = bf2f((unsigned short)bias[mrow_g]);
  else              bv = bias[mrow_g];

  // ---- staging maps ----
  // fp32: thread owns col b=t&31, k in [16*(t>>5), +16): 16 coalesced dwords.
  // bf16: thread owns col-pair 2*(t&15), k in [8*(t>>4), +8): 8 dwords.
  const int fb  = t & 31;
  const int fk0 = (t >> 5) << 4;
  const int hb  = (t & 15) << 1;
  const int hk0 = (t >> 4) << 3;

  float    fs[16];
  unsigned du[8];

  auto stage_load = [&](int j) {
    if constexpr (BF) {
      const T* p = inp + (size_t)(kb * 256 + hk0) * BCOLS + b0 + j * 32 + hb;
#pragma unroll
      for (int r = 0; r < 8; ++r) du[r] = *(const unsigned*)(p + (size_t)r * BCOLS);
    } else {
      const float* p =
          (const float*)inp + (size_t)(kb * 256 + fk0) * BCOLS + b0 + j * 32 + fb;
#pragma unroll
      for (int r = 0; r < 16; ++r) fs[r] = p[(size_t)r * BCOLS];
    }
  };
  auto stage_write = [&](int buf) {
    if constexpr (BF) {
      uint4 c0, c1;
      c0.x = (du[0] & 0xFFFFu) | (du[1] << 16);
      c0.y = (du[2] & 0xFFFFu) | (du[3] << 16);
      c0.z = (du[4] & 0xFFFFu) | (du[5] << 16);
      c0.w = (du[6] & 0xFFFFu) | (du[7] << 16);
      c1.x = (du[0] >> 16) | (du[1] & 0xFFFF0000u);
      c1.y = (du[2] >> 16) | (du[3] & 0xFFFF0000u);
      c1.z = (du[4] >> 16) | (du[5] & 0xFFFF0000u);
      c1.w = (du[6] >> 16) | (du[7] & 0xFFFF0000u);
      *(uint4*)&Blds[buf][hb][hk0]     = c0;
      *(uint4*)&Blds[buf][hb + 1][hk0] = c1;
    } else {
      uint4 a = {pk2(fs[0], fs[1]),  pk2(fs[2], fs[3]),
                 pk2(fs[4], fs[5]),  pk2(fs[6], fs[7])};
      uint4 b = {pk2(fs[8], fs[9]),  pk2(fs[10], fs[11]),
                 pk2(fs[12], fs[13]), pk2(fs[14], fs[15])};
      *(uint4*)&Blds[buf][fb][fk0]     = a;
      *(uint4*)&Blds[buf][fb][fk0 + 8] = b;
    }
  };

  // ---- pipeline prologue ----
  stage_load(0);
  stage_write(0);   // waits own vmcnt (cold, once)
  stage_load(1);    // in flight across the barrier + iter 0 compute
  __syncthreads();

#pragma unroll
  for (int j = 0; j < 4; ++j) {
    const int buf = j & 1;
    f32x16 acc = {};
#pragma unroll
    for (int kk = 0; kk < 16; ++kk) {
      short8 a = *(const short8*)&Blds[buf][l31][kk * 16 + q * 8];
      acc = __builtin_amdgcn_mfma_f32_32x32x16_bf16(a, wf[kk], acc, 0, 0, 0);
    }
    // keep HBM fed: write tile j+1 to the other buffer, then launch j+2 loads
    if (j < 3) stage_write(1 - buf);
    if (j < 2) stage_load(j + 2);
    // store tile j: plain stores (L2 write-combines the 64B half-lines)
    const size_t rowoff = (size_t)mrow_g * BCOLS + b0 + j * 32 + q * 4;
#pragma unroll
    for (int rg = 0; rg < 4; ++rg) {
      const size_t o = rowoff + rg * 8;
      if constexpr (BF) {
        ushort4v p = {f2bf(acc[4 * rg] + bv),     f2bf(acc[4 * rg + 1] + bv),
                      f2bf(acc[4 * rg + 2] + bv), f2bf(acc[4 * rg + 3] + bv)};
        *(ushort4v*)(out + o) = p;
      } else {
        f32x4 p = {acc[4 * rg] + bv,     acc[4 * rg + 1] + bv,
                   acc[4 * rg + 2] + bv, acc[4 * rg + 3] + bv};
        *(f32x4*)((float*)out + o) = p;
      }
    }
    __syncthreads();
  }
}

template <bool WBF>
__global__ __launch_bounds__(512, 4) void BlockLinear_90752658965115_kernel(
    const void* __restrict__ inp, const void* __restrict__ blocks,
    const void* __restrict__ bias, const unsigned short* __restrict__ wbf,
    void* __restrict__ out) {
  __shared__ unsigned short Blds[2][32][264];  // 33 KiB -> 2 wgs/CU
  if (detect_bf16(inp)) {
    run_bl<unsigned short, WBF>((const unsigned short*)inp,
                                (const unsigned short*)blocks, wbf,
                                (const unsigned short*)bias,
                                (unsigned short*)out, Blds);
  } else {
    run_bl<float, WBF>((const float*)inp, (const float*)blocks, wbf,
                       (const float*)bias, (float*)out, Blds);
  }
}

extern "C" void kernel_launch(void* const* d_in, const int* in_sizes, int n_in,
                              void* d_out, int out_size, void* d_ws, size_t ws_size,
                              hipStream_t stream) {
  (void)in_sizes; (void)n_in; (void)out_size;
  const size_t wbytes = (size_t)8 * 256 * 256 * 2;  // 1 MiB bf16 weights
  if (ws_size >= wbytes) {
    bl_convw<<<dim3(512), dim3(256), 0, stream>>>(d_in[1], (unsigned short*)d_ws);
    BlockLinear_90752658965115_kernel<true><<<dim3(512), dim3(512), 0, stream>>>(
        d_in[0], d_in[1], d_in[2], (unsigned short*)d_ws, d_out);
  } else {
    BlockLinear_90752658965115_kernel<false><<<dim3(512), dim3(512), 0, stream>>>(
        d_in[0], d_in[1], d_in[2], nullptr, d_out);
  }
}

// Round 6
// 168.460 us; speedup vs baseline: 1.0192x; 1.0192x over previous
//
#include <hip/hip_runtime.h>
#include <stdint.h>

// BlockLinear: out = block_diag(blocks) @ inp + bias
//   inp (2048,8192) (dtype auto-detected fp32/bf16), blocks (8,256,256), bias (2048,)
// R6: ZERO barriers. R5 post-mortem: (a) __syncthreads forces s_waitcnt vmcnt(0)
// (global-write visibility) -> drains the prefetch, phase-locks all waves;
// (b) per-lane fixed-row 16B stores -> partial-line WRITE inflation (122 MB).
// Fix: weights register-resident per wave (2 mt x 8 ksteps of 16x16x32 frags),
// inp staged into WAVE-PRIVATE LDS (1.25 KB/wave, single buffer -- per-wave DS
// ops are in-order so read(c) < write(c+1) is safe), waves free-run with only
// fine-grained per-wave vmcnt waits; 16 waves/CU provide the latency hiding.
// Epilogue = R2-verified pattern: per instr, 4 quads cover one full 64B line
// per row x 16 rows (clean WRITE). No prepass: weights straight from L2
// (kb = wg&7 pins block + readers to one XCD).

#define BCOLS 8192

typedef __attribute__((ext_vector_type(8))) short short8;             // 8 bf16
typedef __attribute__((ext_vector_type(4))) float f32x4;
typedef __attribute__((ext_vector_type(2))) unsigned u32x2;
typedef __attribute__((ext_vector_type(4))) unsigned u32x4;
typedef __attribute__((ext_vector_type(4))) unsigned short ushort4v;

__device__ __forceinline__ unsigned short f2bf(float x) {
  unsigned u = __builtin_bit_cast(unsigned, x);
  u += 0x7FFFu + ((u >> 16) & 1u);  // RNE
  return (unsigned short)(u >> 16);
}
__device__ __forceinline__ float bf2f(unsigned short h) {
  unsigned u = ((unsigned)h) << 16;
  return __builtin_bit_cast(float, u);
}
__device__ __forceinline__ unsigned pk2(float a, float b) {
  return (unsigned)f2bf(a) | ((unsigned)f2bf(b) << 16);
}

// bf16 data: bits[8:15] of each dword cluster in [0x3B,0x43] for N(0,1);
// fp32: uniform mantissa bits. 32-sample vote, wave-uniform.
__device__ __forceinline__ bool detect_bf16(const void* p) {
  const unsigned* u = (const unsigned*)p;
  int votes = 0;
#pragma unroll
  for (int i = 0; i < 32; ++i) {
    unsigned b = (u[i] >> 8) & 0x7Fu;
    votes += (b >= 0x3Bu && b <= 0x43u) ? 1 : 0;
  }
  return votes >= 16;
}

// wg (512 thr = 8 waves): kb = wg&7, 128-col stripe = (wg>>3)*128.
// wave w: m rows [32w, 32w+32). 8 iters of 16-b slices; per iter 8 chunks of
// 32 k staged wave-privately. MFMA 16x16x32: A = inp^T (LDS, b-major
// k-contiguous) A[i=b=lane&15][k=quad*8+e]; B = weights (regs) B[k][j=m];
// D: col(lane&15)=m, row(quad*4+reg)=b -> quads tile full 64B lines per row.
template <typename T>
__device__ __forceinline__ void run_bl(const T* __restrict__ inp,
                                       const T* __restrict__ blocks,
                                       const T* __restrict__ bias,
                                       T* __restrict__ out,
                                       unsigned short (&L)[16][40]) {
  constexpr bool BF = (sizeof(T) == 2);
  const int t    = threadIdx.x;
  const int wg   = blockIdx.x;
  const int kb   = wg & 7;
  const int s0   = (wg >> 3) << 7;   // stripe base (128 cols)
  const int lane = t & 63;
  const int w    = t >> 6;
  const int l15  = lane & 15;
  const int q4   = lane >> 4;
  const int m0   = w << 5;

  // ---- one-time: weight frags wf[mt][c] (c = k-step of 32) into registers ----
  short8 wf[2][8];
#pragma unroll
  for (int mt = 0; mt < 2; ++mt) {
    const int mrow = m0 + mt * 16 + l15;
    if constexpr (BF) {
      const unsigned short* wr =
          (const unsigned short*)blocks + kb * 65536 + mrow * 256 + q4 * 8;
#pragma unroll
      for (int c = 0; c < 8; ++c) wf[mt][c] = *(const short8*)(wr + c * 32);
    } else {
      const float* wr = (const float*)blocks + kb * 65536 + mrow * 256 + q4 * 8;
#pragma unroll
      for (int c = 0; c < 8; ++c) {
        float4 a = *(const float4*)(wr + c * 32);
        float4 b = *(const float4*)(wr + c * 32 + 4);
        uint4 u = {pk2(a.x, a.y), pk2(a.z, a.w), pk2(b.x, b.y), pk2(b.z, b.w)};
        wf[mt][c] = __builtin_bit_cast(short8, u);
      }
    }
  }
  float bv[2];
#pragma unroll
  for (int mt = 0; mt < 2; ++mt) {
    const int mrow = kb * 256 + m0 + mt * 16 + l15;
    if constexpr (BF) bv[mt] = bf2f((unsigned short)bias[mrow]);
    else              bv[mt] = bias[mrow];
  }

  // staging maps (wave-private; all waves of the wg load the same slice -> L1)
  // fp32: lane (l15=b, q4): 8 rows k = c*32 + q4*8 + r, col s0+j*16+l15.
  // bf16: lane (p=lane&7 b-pair, kq=lane>>3): 4 rows k = c*32+kq*4+r, dword col.
  const int hp = lane & 7;
  const int hk = lane >> 3;

  float    vf[2][8];
  unsigned vh[2][4];

  auto loadC = [&](int j, int c, int s) {
    if constexpr (BF) {
      const unsigned* p = (const unsigned*)(inp + (size_t)(kb * 256 + c * 32 + hk * 4) * BCOLS
                                            + s0 + j * 16) + hp;
#pragma unroll
      for (int r = 0; r < 4; ++r) vh[s][r] = p[(size_t)r * (BCOLS / 2)];
    } else {
      const float* p = (const float*)inp + (size_t)(kb * 256 + c * 32 + q4 * 8) * BCOLS
                       + s0 + j * 16 + l15;
#pragma unroll
      for (int r = 0; r < 8; ++r) vf[s][r] = p[(size_t)r * BCOLS];
    }
  };
  auto packWrite = [&](int s) {
    if constexpr (BF) {
      u32x2 e = {(vh[s][0] & 0xFFFFu) | (vh[s][1] << 16),
                 (vh[s][2] & 0xFFFFu) | (vh[s][3] << 16)};
      u32x2 o = {(vh[s][0] >> 16) | (vh[s][1] & 0xFFFF0000u),
                 (vh[s][2] >> 16) | (vh[s][3] & 0xFFFF0000u)};
      *(u32x2*)&L[hp * 2][hk * 4]     = e;
      *(u32x2*)&L[hp * 2 + 1][hk * 4] = o;
    } else {
      u32x4 d = {pk2(vf[s][0], vf[s][1]), pk2(vf[s][2], vf[s][3]),
                 pk2(vf[s][4], vf[s][5]), pk2(vf[s][6], vf[s][7])};
      *(u32x4*)&L[l15][q4 * 8] = d;
    }
  };

  // ---- main loop: 8 b-slices x 8 k-chunks, no barriers anywhere ----
  for (int j = 0; j < 8; ++j) {
    loadC(j, 0, 0);
    f32x4 acc0 = {0.f, 0.f, 0.f, 0.f}, acc1 = {0.f, 0.f, 0.f, 0.f};
#pragma unroll
    for (int c = 0; c < 8; ++c) {
      if (c < 7) loadC(j, c + 1, (c + 1) & 1);  // next chunk in flight
      packWrite(c & 1);                          // waits own vmcnt only
      short8 af = *(const short8*)&L[l15][q4 * 8];
      acc0 = __builtin_amdgcn_mfma_f32_16x16x32_bf16(af, wf[0][c], acc0, 0, 0, 0);
      acc1 = __builtin_amdgcn_mfma_f32_16x16x32_bf16(af, wf[1][c], acc1, 0, 0, 0);
    }
    // stores: R2 pattern -- quads tile 64B per row, 16 rows per instruction
#pragma unroll
    for (int mt = 0; mt < 2; ++mt) {
      const f32x4 a = mt ? acc1 : acc0;
      const size_t o = (size_t)(kb * 256 + m0 + mt * 16 + l15) * BCOLS
                       + s0 + j * 16 + q4 * 4;
      if constexpr (BF) {
        ushort4v p = {f2bf(a[0] + bv[mt]), f2bf(a[1] + bv[mt]),
                      f2bf(a[2] + bv[mt]), f2bf(a[3] + bv[mt])};
        *(ushort4v*)(out + o) = p;
      } else {
        f32x4 p = {a[0] + bv[mt], a[1] + bv[mt], a[2] + bv[mt], a[3] + bv[mt]};
        *(f32x4*)((float*)out + o) = p;
      }
    }
  }
}

__global__ __launch_bounds__(512, 4) void BlockLinear_90752658965115_kernel(
    const void* __restrict__ inp, const void* __restrict__ blocks,
    const void* __restrict__ bias, void* __restrict__ out) {
  // wave-private LDS: 8 waves x 16 b-rows x (32 k + 8 pad) bf16 = 10 KiB/wg
  __shared__ unsigned short Blds[8][16][40];
  const int w = threadIdx.x >> 6;
  if (detect_bf16(inp)) {
    run_bl<unsigned short>((const unsigned short*)inp,
                           (const unsigned short*)blocks,
                           (const unsigned short*)bias,
                           (unsigned short*)out, Blds[w]);
  } else {
    run_bl<float>((const float*)inp, (const float*)blocks,
                  (const float*)bias, (float*)out, Blds[w]);
  }
}

extern "C" void kernel_launch(void* const* d_in, const int* in_sizes, int n_in,
                              void* d_out, int out_size, void* d_ws, size_t ws_size,
                              hipStream_t stream) {
  (void)in_sizes; (void)n_in; (void)d_ws; (void)ws_size; (void)out_size;
  // 8 k-blocks x 64 stripes of 128 cols = 512 wgs x 512 thr (2 wgs/CU).
  BlockLinear_90752658965115_kernel<<<dim3(512), dim3(512), 0, stream>>>(
      d_in[0], d_in[1], d_in[2], d_out);
}